// Round 4
// baseline (348.332 us; speedup 1.0000x reference)
//
#include <hip/hip_runtime.h>

#define D 64
#define WQ_BITS 15
#define WQ_MAX 32767.0f
#define NSHARDS 8
#define CAP32 32        // tier-2 (node-sharded) bucket capacity
#define CAPX 8          // tier-1 per-(node,XCD) bucket capacity: deg~Poisson(16)
                        // split 8 ways -> Poisson(2)/bucket; P(>8)~2e-4 ->
                        // ~300 edges total to overflow path.

typedef int   int4v   __attribute__((ext_vector_type(4)));
typedef float float4v __attribute__((ext_vector_type(4)));

__device__ __forceinline__ ushort f2bf(float x) {
    unsigned u = __float_as_uint(x);
    unsigned r = (u + 0x7fff + ((u >> 16) & 1)) >> 16;  // round-to-nearest-even
    return (ushort)r;
}
__device__ __forceinline__ float bf2f(ushort u) {
    return __uint_as_float(((unsigned)u) << 16);
}
__device__ __forceinline__ unsigned get_xcc_id() {
    unsigned x;
    asm volatile("s_getreg_b32 %0, hwreg(HW_REG_XCC_ID)" : "=s"(x));
    return x & 7u;
}

// ---------------------------------------------------------------------------
// Round-13 tier-1 scatter: single edge pass; pairs partitioned by the PHYSICAL
// XCD of the executing block (HW_REG_XCC_ID). Coherence ledger:
//  r2: plain stores, cross-XCD rows -> replay corruption (L2s not coherent).
//  r3: agent-scope atomic stores -> correct but 64B write-through per 4B store
//      (WRITE 99.9MB, dur 96us; worse than r1's 8x-scan 78us).
//  now: region exclusivity by construction (all writers of pairs[xcc] share
//      that XCD's L2) -> plain stores legal, lines writeback once, region
//      3.2MB/XCD is L2-resident, edges scanned once.
__global__ __launch_bounds__(256) void scatter_xcd_kernel(
    const int* __restrict__ src, const int* __restrict__ dst,
    const float* __restrict__ w, int* __restrict__ cursor,
    unsigned* __restrict__ ovBits, unsigned* __restrict__ pairs,
    int E, int N)
{
    unsigned xcc = get_xcc_id();
    int*      mycur   = cursor + (size_t)xcc * N;
    unsigned* mypairs = pairs  + (size_t)xcc * N * CAPX;

    int e4 = E >> 2;
    for (int gi = blockIdx.x * 256 + threadIdx.x; gi < e4;
         gi += gridDim.x * 256) {
        int e0 = gi * 4;
        int4v   d4 = __builtin_nontemporal_load((const int4v*)&dst[e0]);
        int4v   s4 = __builtin_nontemporal_load((const int4v*)&src[e0]);
        float4v w4 = __builtin_nontemporal_load((const float4v*)&w[e0]);
        #pragma unroll
        for (int i = 0; i < 4; ++i) {
            int d = d4[i];
            int pos = atomicAdd(&mycur[d], 1);
            if (pos < CAPX) {
                float wv = fminf(fmaxf(w4[i], 0.f), 1.f);
                unsigned wq = (unsigned)(wv * WQ_MAX + 0.5f);
                mypairs[(size_t)d * CAPX + pos] =
                    ((unsigned)s4[i] << WQ_BITS) | wq;
            } else {
                int e = e0 + i;
                atomicOr(&ovBits[e >> 5], 1u << (e & 31));
            }
        }
    }
    for (int e = e4 * 4 + blockIdx.x * 256 + threadIdx.x; e < E;
         e += gridDim.x * 256) {
        int d = dst[e];
        int pos = atomicAdd(&mycur[d], 1);
        if (pos < CAPX) {
            float wv = fminf(fmaxf(w[e], 0.f), 1.f);
            unsigned wq = (unsigned)(wv * WQ_MAX + 0.5f);
            mypairs[(size_t)d * CAPX + pos] =
                ((unsigned)src[e] << WQ_BITS) | wq;
        } else {
            atomicOr(&ovBits[e >> 5], 1u << (e & 31));
        }
    }
}

// ---------------------------------------------------------------------------
// Tier-2 scatter (round-1 verified): node-sharded, shard=blockIdx%8 -> one XCD
// owns each node's bucket row; costs an 8x edge scan. Used only if ws too
// small for the per-XCD layout.
__global__ __launch_bounds__(256) void shard_scatter_kernel(
    const int* __restrict__ src, const int* __restrict__ dst,
    const float* __restrict__ w, int* __restrict__ cursor,
    unsigned* __restrict__ ovBits, unsigned* __restrict__ pairs,
    int E, int N)
{
    int shard   = blockIdx.x & (NSHARDS - 1);
    int slice   = blockIdx.x >> 3;
    int nSlices = gridDim.x >> 3;
    int n8 = (N + NSHARDS - 1) / NSHARDS;
    int lo = shard * n8;
    int hi = min(N, lo + n8);

    int e4 = E >> 2;
    for (int gi = slice * 256 + threadIdx.x; gi < e4; gi += nSlices * 256) {
        int e0 = gi * 4;
        int4v   d4 = __builtin_nontemporal_load((const int4v*)&dst[e0]);
        int4v   s4 = __builtin_nontemporal_load((const int4v*)&src[e0]);
        float4v w4 = __builtin_nontemporal_load((const float4v*)&w[e0]);
        #pragma unroll
        for (int i = 0; i < 4; ++i) {
            int d = d4[i];
            if (d >= lo && d < hi) {
                int e = e0 + i;
                int pos = atomicAdd(&cursor[d], 1);
                if (pos < CAP32) {
                    float wv = fminf(fmaxf(w4[i], 0.f), 1.f);
                    unsigned wq = (unsigned)(wv * WQ_MAX + 0.5f);
                    pairs[(size_t)d * CAP32 + pos] =
                        ((unsigned)s4[i] << WQ_BITS) | wq;
                } else {
                    atomicOr(&ovBits[e >> 5], 1u << (e & 31));
                }
            }
        }
    }
    for (int e = e4 * 4 + slice * 256 + threadIdx.x; e < E; e += nSlices * 256) {
        int d = dst[e];
        if (d >= lo && d < hi) {
            int pos = atomicAdd(&cursor[d], 1);
            if (pos < CAP32) {
                float wv = fminf(fmaxf(w[e], 0.f), 1.f);
                unsigned wq = (unsigned)(wv * WQ_MAX + 0.5f);
                pairs[(size_t)d * CAP32 + pos] =
                    ((unsigned)src[e] << WQ_BITS) | wq;
            } else {
                atomicOr(&ovBits[e >> 5], 1u << (e & 31));
            }
        }
    }
}

// ---------------------------------------------------------------------------
// Fused GEMM: out[n][j] = b[j] + sum_k h[n][k]*W[j][k]        (fp32)
//             g[n][j]   =        sum_k h[n][k]*W[j][64+k]     (bf16 store)
__global__ __launch_bounds__(256) void gemm_fused_kernel(
    const float* __restrict__ h, const float* __restrict__ W,
    const float* __restrict__ b, float* __restrict__ out,
    ushort* __restrict__ g, int N)
{
    __shared__ float Wt[128 * 64];
    __shared__ float Xt[64 * 64];
    int tid = threadIdx.x;

    for (int idx = tid; idx < 128 * 64; idx += 256) {
        int j = idx & 63;
        int k = idx >> 6;
        Wt[k * 64 + j] = W[j * 128 + k];
    }

    int n0blk = blockIdx.x * 64;
    {
        int n = tid & 63;
        int krow = tid >> 6;
        int nn = min(n0blk + n, N - 1);
        #pragma unroll
        for (int c = 0; c < 4; ++c) {
            int k0 = (krow + c * 4) * 4;
            float4 v = *(const float4*)&h[(size_t)nn * D + k0];
            Xt[(k0 + 0) * 64 + n] = v.x;
            Xt[(k0 + 1) * 64 + n] = v.y;
            Xt[(k0 + 2) * 64 + n] = v.z;
            Xt[(k0 + 3) * 64 + n] = v.w;
        }
    }
    __syncthreads();

    int j0 = (tid & 15) * 4;
    int nb = (tid >> 4) * 4;

    float4 bv = *(const float4*)&b[j0];
    float accS[4][4], accG[4][4];
    #pragma unroll
    for (int i = 0; i < 4; ++i) {
        accS[i][0] = bv.x; accS[i][1] = bv.y; accS[i][2] = bv.z; accS[i][3] = bv.w;
        accG[i][0] = 0.f;  accG[i][1] = 0.f;  accG[i][2] = 0.f;  accG[i][3] = 0.f;
    }

    #pragma unroll 4
    for (int k = 0; k < 64; ++k) {
        float4 xv = *(const float4*)&Xt[k * 64 + nb];
        float4 w1 = *(const float4*)&Wt[k * 64 + j0];
        float4 w2 = *(const float4*)&Wt[(k + 64) * 64 + j0];
        #pragma unroll
        for (int i = 0; i < 4; ++i) {
            float x = (&xv.x)[i];
            accS[i][0] += x * w1.x; accS[i][1] += x * w1.y;
            accS[i][2] += x * w1.z; accS[i][3] += x * w1.w;
            accG[i][0] += x * w2.x; accG[i][1] += x * w2.y;
            accG[i][2] += x * w2.z; accG[i][3] += x * w2.w;
        }
    }

    #pragma unroll
    for (int i = 0; i < 4; ++i) {
        int n = n0blk + nb + i;
        if (n < N) {
            *(float4*)&out[(size_t)n * D + j0] =
                make_float4(accS[i][0], accS[i][1], accS[i][2], accS[i][3]);
            ushort4 gv;
            gv.x = f2bf(accG[i][0]); gv.y = f2bf(accG[i][1]);
            gv.z = f2bf(accG[i][2]); gv.w = f2bf(accG[i][3]);
            *(ushort4*)&g[(size_t)n * D + j0] = gv;
        }
    }
}

// ---------------------------------------------------------------------------
// Tier-1 final agg: node n's codes live in 8 per-XCD buckets of CAPX=8.
// lane = x*8+slot loads bucket x slot s (one load/lane); validity ballot is
// wave-uniform -> compact via ffs chain, then batched shfl+gather (MLP 16).
__global__ __launch_bounds__(256) void final_agg_xcd_kernel(
    const ushort* __restrict__ g, const unsigned* __restrict__ pairs,
    const int* __restrict__ cursor, float* __restrict__ out, int N)
{
    int wave = threadIdx.x >> 6;
    int lane = threadIdx.x & 63;
    int n = blockIdx.x * 4 + wave;
    if (n >= N) return;

    int x    = lane >> 3;   // XCD region 0..7
    int slot = lane & 7;    // slot within bucket
    int cnt_x = min(cursor[(size_t)x * N + n], CAPX);
    unsigned mycode = pairs[((size_t)x * N + n) * CAPX + slot];
    bool valid = slot < cnt_x;
    unsigned long long m = __ballot(valid);

    float acc = out[(size_t)n * D + lane];
    const float wscale = 1.0f / WQ_MAX;

    while (m) {
        unsigned c[16];
        float v[16];
        int k = 0;
        #pragma unroll
        for (int u = 0; u < 16; ++u) {
            if (m) {  // wave-uniform (ballot result)
                int l = (int)__ffsll(m) - 1;
                m &= m - 1;
                c[u] = __shfl(mycode, l);
                k = u + 1;
            }
        }
        #pragma unroll
        for (int u = 0; u < 16; ++u)
            if (u < k) v[u] = bf2f(g[(size_t)(c[u] >> WQ_BITS) * D + lane]);
        #pragma unroll
        for (int u = 0; u < 16; ++u)
            if (u < k) acc += (float)(c[u] & 0x7fffu) * wscale * v[u];
    }
    out[(size_t)n * D + lane] = acc;
}

// ---------------------------------------------------------------------------
// Tier-2 final agg (round-1 verified): single CAP32 bucket per node.
__global__ __launch_bounds__(256) void final_agg32_kernel(
    const ushort* __restrict__ g, const unsigned* __restrict__ pairs,
    const int* __restrict__ cursor, float* __restrict__ out, int N)
{
    int wave = threadIdx.x >> 6;
    int lane = threadIdx.x & 63;
    int n = blockIdx.x * 4 + wave;
    if (n >= N) return;
    int cnt = min(cursor[n], CAP32);
    unsigned mycode = (lane < CAP32) ? pairs[(size_t)n * CAP32 + lane] : 0u;
    float acc = out[(size_t)n * D + lane];

    const float wscale = 1.0f / WQ_MAX;
    int j = 0;
    for (; j + 16 <= cnt; j += 16) {
        unsigned c[16];
        float v[16];
        #pragma unroll
        for (int u = 0; u < 16; ++u) c[u] = __shfl(mycode, j + u);
        #pragma unroll
        for (int u = 0; u < 16; ++u)
            v[u] = bf2f(g[(size_t)(c[u] >> WQ_BITS) * D + lane]);
        #pragma unroll
        for (int u = 0; u < 16; ++u)
            acc += (float)(c[u] & 0x7fffu) * wscale * v[u];
    }
    for (; j + 4 <= cnt; j += 4) {
        unsigned c[4];
        float v[4];
        #pragma unroll
        for (int u = 0; u < 4; ++u) c[u] = __shfl(mycode, j + u);
        #pragma unroll
        for (int u = 0; u < 4; ++u)
            v[u] = bf2f(g[(size_t)(c[u] >> WQ_BITS) * D + lane]);
        #pragma unroll
        for (int u = 0; u < 4; ++u)
            acc += (float)(c[u] & 0x7fffu) * wscale * v[u];
    }
    for (; j < cnt; ++j) {
        unsigned c = __shfl(mycode, j);
        acc += (float)(c & 0x7fffu) * wscale *
               bf2f(g[(size_t)(c >> WQ_BITS) * D + lane]);
    }
    out[(size_t)n * D + lane] = acc;
}

// ---------------------------------------------------------------------------
// Overflow cleanup (fp32-exact, runs after final_agg).
__global__ __launch_bounds__(256) void overflow_kernel(
    const unsigned* __restrict__ ovBits, const int* __restrict__ src,
    const int* __restrict__ dst, const float* __restrict__ w,
    const ushort* __restrict__ g, float* __restrict__ out, int numWords)
{
    int idx = blockIdx.x * 256 + threadIdx.x;
    for (int wi = idx; wi < numWords; wi += gridDim.x * 256) {
        unsigned bits = ovBits[wi];
        while (bits) {
            int bit = __ffs(bits) - 1;
            bits &= bits - 1;
            int e = wi * 32 + bit;
            int s = src[e], d = dst[e];
            float wv = w[e];
            for (int f = 0; f < D; ++f)
                atomicAdd(&out[(size_t)d * D + f], wv * bf2f(g[(size_t)s * D + f]));
        }
    }
}

// ---------------------------------------------------------------------------
// Fallback path (small ws / big N): round-1 kernels, known-good.
__global__ __launch_bounds__(256) void edge_scatter_kernel(
    const float* __restrict__ h, const float* __restrict__ w,
    const int* __restrict__ src, const int* __restrict__ dst,
    float* __restrict__ agg, int E)
{
    int e = blockIdx.x * 4 + (threadIdx.x >> 6);
    int lane = threadIdx.x & 63;
    if (e >= E) return;
    float val = w[e] * h[(size_t)src[e] * D + lane];
    atomicAdd(&agg[(size_t)dst[e] * D + lane], val);
}

__global__ __launch_bounds__(256) void out_linear_kernel(
    const float* __restrict__ h, const float* __restrict__ agg,
    const float* __restrict__ W, const float* __restrict__ b,
    float* __restrict__ out, int N)
{
    __shared__ float Wt[128 * 64];
    int lane = threadIdx.x & 63;
    int waveInBlock = threadIdx.x >> 6;
    int wavesPerBlock = blockDim.x >> 6;
    for (int idx = threadIdx.x; idx < 128 * 64; idx += blockDim.x) {
        int j = idx & 63;
        int k = idx >> 6;
        Wt[k * 64 + j] = W[j * 128 + k];
    }
    __syncthreads();
    float bj = b[lane];
    int wavesPerGrid = gridDim.x * wavesPerBlock;
    for (int n = blockIdx.x * wavesPerBlock + waveInBlock; n < N; n += wavesPerGrid) {
        float hreg = h[(size_t)n * D + lane];
        float areg = agg[(size_t)n * D + lane];
        float acc = bj;
        #pragma unroll
        for (int k = 0; k < 64; ++k) {
            float hk = __shfl(hreg, k, 64);
            float ak = __shfl(areg, k, 64);
            acc += hk * Wt[k * 64 + lane];
            acc += ak * Wt[(k + 64) * 64 + lane];
        }
        out[(size_t)n * D + lane] = acc;
    }
}

// ---------------------------------------------------------------------------
extern "C" void kernel_launch(void* const* d_in, const int* in_sizes, int n_in,
                              void* d_out, int out_size, void* d_ws, size_t ws_size,
                              hipStream_t stream) {
    const float* h   = (const float*)d_in[0];
    const float* w   = (const float*)d_in[1];
    const int*   src = (const int*)d_in[2];
    const int*   dst = (const int*)d_in[3];
    const float* W   = (const float*)d_in[4];
    const float* b   = (const float*)d_in[5];
    float* out = (float*)d_out;

    int N = in_sizes[0] / D;
    int E = in_sizes[1];
    int numWords = (E + 31) / 32;

    auto align256 = [](size_t x) { return (x + 255) & ~(size_t)255; };
    size_t ovB = align256((size_t)numWords * 4);
    size_t gB  = align256((size_t)N * D * 2);

    // tier-1: per-XCD regions (8x cursor, 8x CAPX pairs)
    size_t cursorB1 = align256((size_t)N * 8 * 4);
    size_t pairsB1  = align256((size_t)N * 8 * CAPX * 4);
    size_t need1 = cursorB1 + ovB + pairsB1 + gB;
    // tier-2: node-sharded CAP32
    size_t cursorB2 = align256((size_t)N * 4);
    size_t pairsB2  = align256((size_t)N * CAP32 * 4);
    size_t need2 = cursorB2 + ovB + pairsB2 + gB;

    if (ws_size >= need1 && N <= (1 << 17)) {
        char* p = (char*)d_ws;
        int*      cursor = (int*)p;       p += cursorB1;
        unsigned* ovBits = (unsigned*)p;  p += ovB;
        unsigned* pairs  = (unsigned*)p;  p += pairsB1;
        ushort*   g      = (ushort*)p;

        hipMemsetAsync(cursor, 0, cursorB1 + ovB, stream);

        int e4 = E >> 2;
        int scatterBlocks = min(2048, max(1, (e4 + 255) / 256));
        scatter_xcd_kernel<<<scatterBlocks, 256, 0, stream>>>(
            src, dst, w, cursor, ovBits, pairs, E, N);
        gemm_fused_kernel<<<(N + 63) / 64, 256, 0, stream>>>(h, W, b, out, g, N);
        final_agg_xcd_kernel<<<(N + 3) / 4, 256, 0, stream>>>(g, pairs, cursor,
                                                              out, N);
        overflow_kernel<<<64, 256, 0, stream>>>(ovBits, src, dst, w, g, out,
                                                numWords);
    } else if (ws_size >= need2 && N <= (1 << 17)) {
        char* p = (char*)d_ws;
        int*      cursor = (int*)p;       p += cursorB2;
        unsigned* ovBits = (unsigned*)p;  p += ovB;
        unsigned* pairs  = (unsigned*)p;  p += pairsB2;
        ushort*   g      = (ushort*)p;

        hipMemsetAsync(cursor, 0, cursorB2 + ovB, stream);

        shard_scatter_kernel<<<4096, 256, 0, stream>>>(src, dst, w, cursor,
                                                       ovBits, pairs, E, N);
        gemm_fused_kernel<<<(N + 63) / 64, 256, 0, stream>>>(h, W, b, out, g, N);
        final_agg32_kernel<<<(N + 3) / 4, 256, 0, stream>>>(g, pairs, cursor,
                                                            out, N);
        overflow_kernel<<<64, 256, 0, stream>>>(ovBits, src, dst, w, g, out,
                                                numWords);
    } else {
        float* agg = out;
        hipMemsetAsync(agg, 0, (size_t)N * D * 4, stream);
        edge_scatter_kernel<<<(E + 3) / 4, 256, 0, stream>>>(h, w, src, dst, agg, E);
        out_linear_kernel<<<2048, 256, 0, stream>>>(h, agg, W, b, out, N);
    }
}